// Round 3
// baseline (272.257 us; speedup 1.0000x reference)
//
#include <hip/hip_runtime.h>
#include <hip/hip_bf16.h>

// BLAST factorized linear, fused:
//   Stage A (no barriers): T[n, j*128+r] = sum_s X[n, j*256+s]*Vt[j,s,r]
//       swapped MFMA (D=[r,n]); lane writes its 8 T values to swizzled T_lds.
//   Stage B (1 barrier per o): u[n,r] = sum_j S[o,j,r]*T[n,j*128+r]  (VALU)
//       -> u_lds[o&1] (dbuf) -> barrier -> out[n,o*256+p] = bias + u @ U_o
//       swapped MFMA (D=[p,n]) -> f32x4 stores.
// 16 rows/wg, 512 wg, 72KB LDS -> 2 wg/CU.

typedef __bf16 bf16x8 __attribute__((ext_vector_type(8)));
typedef __bf16 bf16x4 __attribute__((ext_vector_type(4)));
typedef float  f32x4  __attribute__((ext_vector_type(4)));

#define IN_DIM  4096
#define OUT_DIM 4096
#define NROWS   8192
#define BJ      16
#define BO      16
#define BS_IN   256
#define BS_OUT  256
#define RANK    128

__device__ __forceinline__ bf16x8 cvt8(f32x4 lo, f32x4 hi) {
  bf16x8 r;
  r[0] = (__bf16)lo[0]; r[1] = (__bf16)lo[1]; r[2] = (__bf16)lo[2]; r[3] = (__bf16)lo[3];
  r[4] = (__bf16)hi[0]; r[5] = (__bf16)hi[1]; r[6] = (__bf16)hi[2]; r[7] = (__bf16)hi[3];
  return r;
}

// prep: Vt (16,256,128) fp32 -> vt_t[j][r][s] bf16 ; U (16,128,256) fp32 -> u_t[o][p][r] bf16
__global__ __launch_bounds__(256) void prep_kernel(
    const float* __restrict__ Vt, const float* __restrict__ U,
    __bf16* __restrict__ vt_t, __bf16* __restrict__ u_t)
{
  const int NV = BJ * RANK * BS_IN;   // 524288
  int idx = blockIdx.x * 256 + threadIdx.x;
  if (idx < NV) {
    int j = idx >> 15;
    int r = (idx >> 8) & (RANK - 1);
    int s = idx & (BS_IN - 1);
    vt_t[idx] = (__bf16)Vt[(j * BS_IN + s) * RANK + r];
  } else {
    int k = idx - NV;
    int o = k >> 15;
    int p = (k >> 7) & (BS_OUT - 1);
    int r = k & (RANK - 1);
    u_t[k] = (__bf16)U[(o * RANK + r) * BS_OUT + p];
  }
}

__global__ __launch_bounds__(256, 2) void blast_main(
    const float* __restrict__ x, const float* __restrict__ S,
    const float* __restrict__ bias,
    const __bf16* __restrict__ vt_t, const __bf16* __restrict__ u_t,
    float* __restrict__ out)
{
  // T_lds[n][2048]: elem c at row n lives in 16B-slot s=c>>3 swizzled s^n.
  __shared__ __bf16 T_lds[16 * 2048];      // 64 KB
  // u_lds[buf][n][128]: 8-elem chunk rc at row n lives at slot (rc^n).
  __shared__ __bf16 u_lds[2][16 * 128];    // 2 x 4 KB

  const int tid  = threadIdx.x;
  const int lane = tid & 63;
  const int w    = tid >> 6;       // wave 0..3
  const int l15  = lane & 15;
  const int lhi  = lane >> 4;
  const size_t rowbase = (size_t)blockIdx.x * 16;

  // ---------------- Stage A (barrier-free) ----------------
  // wave w computes T rows r = w*32 .. w*32+31 for all 16 n.
  // D=[r,n]: lane holds (n=l15, r=w*32 + t*16 + lhi*4 + v)
  const float* xrow = x + (rowbase + l15) * IN_DIM;
  for (int j = 0; j < BJ; ++j) {
    f32x4 t0 = {0.f,0.f,0.f,0.f}, t1 = {0.f,0.f,0.f,0.f};
    const float*  xp = xrow + j * BS_IN;
    const __bf16* vb = vt_t + ((size_t)j * RANK + w * 32 + l15) * BS_IN;
    #pragma unroll
    for (int ks = 0; ks < 8; ++ks) {              // K = 256 = 8*32
      const int kc = ks * 32 + lhi * 8;
      const f32x4 xlo = *(const f32x4*)(xp + kc);
      const f32x4 xhi = *(const f32x4*)(xp + kc + 4);
      const bf16x8 xb = cvt8(xlo, xhi);
      const bf16x8 a0 = *(const bf16x8*)(vb + kc);
      const bf16x8 a1 = *(const bf16x8*)(vb + 16 * BS_IN + kc);
      t0 = __builtin_amdgcn_mfma_f32_16x16x32_bf16(a0, xb, t0, 0, 0, 0);
      t1 = __builtin_amdgcn_mfma_f32_16x16x32_bf16(a1, xb, t1, 0, 0, 0);
    }
    // elem c = j*128 + r ; slot s = c>>3 = j*16 + w*4 + (lhi>>1) (+2 for t=1)
    bf16x4 b0, b1;
    b0[0]=(__bf16)t0[0]; b0[1]=(__bf16)t0[1]; b0[2]=(__bf16)t0[2]; b0[3]=(__bf16)t0[3];
    b1[0]=(__bf16)t1[0]; b1[1]=(__bf16)t1[1]; b1[2]=(__bf16)t1[2]; b1[3]=(__bf16)t1[3];
    const int tb  = j * 16 + w * 4 + (lhi >> 1);
    const int inn = (lhi & 1) * 4;
    *(bf16x4*)&T_lds[l15 * 2048 + ((tb ^ l15) << 3) + inn]       = b0;
    *(bf16x4*)&T_lds[l15 * 2048 + (((tb + 2) ^ l15) << 3) + inn] = b1;
  }
  __syncthreads();

  // ---------------- Stage B: one barrier per o ----------------
  const int fn = tid & 15;        // fold: row n
  const int rc = tid >> 4;        // fold: r-chunk 0..15 (8 r each)
  const float* orow = out + (rowbase + l15) * OUT_DIM;

  for (int o = 0; o < BO; ++o) {
    // fold: u[fn][rc*8..+8] = sum_j S[o,j,r]*T[fn][j*128+r]
    f32x4 ua = {0.f,0.f,0.f,0.f}, ubk = {0.f,0.f,0.f,0.f};
    const float* sp = S + (size_t)o * BJ * RANK + rc * 8;
    #pragma unroll
    for (int j = 0; j < BJ; ++j) {
      const bf16x8 tv = *(const bf16x8*)&T_lds[fn * 2048 + (((j * 16 + rc) ^ fn) << 3)];
      const f32x4 s0 = *(const f32x4*)(sp + j * RANK);
      const f32x4 s1 = *(const f32x4*)(sp + j * RANK + 4);
      const f32x4 tlo = {(float)tv[0], (float)tv[1], (float)tv[2], (float)tv[3]};
      const f32x4 thi = {(float)tv[4], (float)tv[5], (float)tv[6], (float)tv[7]};
      ua  = s0 * tlo + ua;
      ubk = s1 * thi + ubk;
    }
    {
      bf16x8 uw;
      uw[0]=(__bf16)ua[0];  uw[1]=(__bf16)ua[1];  uw[2]=(__bf16)ua[2];  uw[3]=(__bf16)ua[3];
      uw[4]=(__bf16)ubk[0]; uw[5]=(__bf16)ubk[1]; uw[6]=(__bf16)ubk[2]; uw[7]=(__bf16)ubk[3];
      *(bf16x8*)&u_lds[o & 1][fn * 128 + ((rc ^ fn) << 3)] = uw;
    }
    __syncthreads();

    // MFMA: out cols [o*256 + w*64, +64), D=[p,n]
    bf16x8 ufrag[4];
    #pragma unroll
    for (int ks = 0; ks < 4; ++ks)
      ufrag[ks] = *(const bf16x8*)&u_lds[o & 1][l15 * 128 + (((ks * 4 + lhi) ^ l15) << 3)];

    const __bf16* ut = u_t + ((size_t)o * BS_OUT + w * 64 + l15) * RANK;
    f32x4 acc[4];
    #pragma unroll
    for (int cf = 0; cf < 4; ++cf) acc[cf] = (f32x4){0.f,0.f,0.f,0.f};
    #pragma unroll
    for (int cf = 0; cf < 4; ++cf) {
      #pragma unroll
      for (int ks = 0; ks < 4; ++ks) {
        const bf16x8 af = *(const bf16x8*)(ut + (size_t)(cf * 16) * RANK + ks * 32 + lhi * 8);
        acc[cf] = __builtin_amdgcn_mfma_f32_16x16x32_bf16(af, ufrag[ks], acc[cf], 0, 0, 0);
      }
    }
    #pragma unroll
    for (int cf = 0; cf < 4; ++cf) {
      const int col = o * BS_OUT + w * 64 + cf * 16 + lhi * 4;
      const f32x4 bv = *(const f32x4*)(bias + col);
      *(f32x4*)(orow + col) = acc[cf] + bv;
    }
    // no trailing barrier: next fold writes the other u_lds buffer;
    // buffer o&1 is next written at o+2, separated by barrier(o+1).
  }
}

extern "C" void kernel_launch(void* const* d_in, const int* in_sizes, int n_in,
                              void* d_out, int out_size, void* d_ws, size_t ws_size,
                              hipStream_t stream) {
  const float* x    = (const float*)d_in[0];
  const float* S    = (const float*)d_in[1];
  const float* U    = (const float*)d_in[2];
  const float* Vt   = (const float*)d_in[3];
  const float* bias = (const float*)d_in[4];
  float* out = (float*)d_out;

  __bf16* vt_t = (__bf16*)d_ws;                    // 1 MB
  __bf16* u_t  = vt_t + (size_t)BJ * RANK * BS_IN; // 1 MB

  const int prep_elems = BJ * RANK * BS_IN + BO * BS_OUT * RANK; // 1048576
  prep_kernel<<<prep_elems / 256, 256, 0, stream>>>(Vt, U, vt_t, u_t);
  blast_main<<<NROWS / 16, 256, 0, stream>>>(x, S, bias, vt_t, u_t, out);
}